// Round 6
// baseline (27483.667 us; speedup 1.0000x reference)
//
#include <hip/hip_runtime.h>
#include <math.h>

#define NB 64      // total batch
#define TT 512     // time steps
#define IN 128     // input dim
#define HD 512     // hidden dim
#define BGN 4      // batch groups
#define BGB 16     // batches per group
#define RBN 64     // row-blocks per batch group  (BGN*RBN = 256 blocks)

__device__ __forceinline__ float sigf(float x) { return 1.0f / (1.0f + expf(-x)); }
__device__ __forceinline__ float dot4(float4 a, float4 b) {
    return a.x*b.x + a.y*b.y + a.z*b.z + a.w*b.w;
}

// 5-stage butterfly over 64 lanes with 32 partials/lane + final half-sum.
// Entry: lane l holds A[j], j=0..31 = its k-slice's partial for output j.
// Exit: lanes l and l^32 both hold the full 64-lane sum for output j = l&31.
// (Same invariant as the verified 64-wide version, stopped one stage early:
//  after 5 stages lane l holds its 32-lane half's sum of A_orig[l&31];
//  the xor-32 add combines the two halves.)
__device__ __forceinline__ float wave_reduce32(float* A, int l) {
    #pragma unroll
    for (int s = 0; s < 5; ++s) {
        const int m = 1 << s;
        const bool bit = (l >> s) & 1;
        const int cnt = 16 >> s;           // 16,8,4,2,1
        #pragma unroll
        for (int i = 0; i < cnt; ++i) {
            float send = bit ? A[2*i]     : A[2*i + 1];
            float keep = bit ? A[2*i + 1] : A[2*i];
            float recv = __shfl_xor(send, m, 64);
            A[i] = keep + recv;
        }
    }
    float v = A[0];
    v += __shfl_xor(v, 32, 64);
    return v;
}

// ws layout (floats): h0T[2][HD][NB] | h2T[2][HD][NB] | flags (ints, 64B-strided)
// Pipeline step s: L0 computes h0_s from h0_{s-1}; L1 computes h2_{s-1} from
// h0_{s-1} and h2_{s-2}.  cur=s&1: read h0T[cur^1], h2T[cur]; write h0T[cur],
// h2T[cur^1]  (identical to the verified Round-0/2/3/4 convention).
__global__ __launch_bounds__(512, 2) void lstm_persist(
    const float* __restrict__ x,
    const float* __restrict__ Wih0, const float* __restrict__ Whh0,
    const float* __restrict__ bih0, const float* __restrict__ bhh0,
    const float* __restrict__ Wih1, const float* __restrict__ Whh1,
    const float* __restrict__ bih1, const float* __restrict__ bhh1,
    const float* __restrict__ fcW, const float* __restrict__ fcb,
    float* __restrict__ ws, float* __restrict__ out)
{
    __shared__ float x_lds[BGB][IN];    // 8 KB
    __shared__ float h0_lds[BGB][HD];   // 32 KB   [b][u'] transposed
    __shared__ float h2_lds[BGB][HD];   // 32 KB

    const int tid = threadIdx.x;
    const int l   = tid & 63;          // lane
    const int w   = tid >> 6;          // wave 0..7
    const int bg  = blockIdx.x & 3;    // batch group
    const int rb  = blockIdx.x >> 2;   // row-block 0..63
    const int u   = rb * 8 + w;        // unit owned by this wave (both layers)
    const int us  = __builtin_amdgcn_readfirstlane(u);  // provably wave-uniform
    const int bg16 = bg * BGB;
    const int bl  = l & 15;            // state-batch lane

    float* h0T = ws;                       // [2][HD][NB]
    float* h2T = ws + 2 * HD * NB;         // [2][HD][NB]
    int*  flags = (int*)(ws + 4 * HD * NB);

    float c0r = 0.0f, c2r = 0.0f;      // cell state, valid on lanes 0..15

    int* myflag = flags + bg * 16;     // 64B-strided

    for (int s = 0; s <= TT; ++s) {
        // ---- T14: issue x load for step s before the barrier (x is input) ----
        float4 xpf;
        const int xb = tid >> 5, xi = (tid & 31) * 4;
        if (s < TT)
            xpf = *(const float4*)(x + ((size_t)(bg16 + xb) * TT + s) * IN + xi);

        // ---- batch-group barrier: single poller per block ----
        const int target = RBN * s;
        if (s > 0) {
            if (tid == 0) {
                int spins = 0;
                while (__hip_atomic_load(myflag, __ATOMIC_RELAXED,
                                         __HIP_MEMORY_SCOPE_AGENT) < target) {
                    __builtin_amdgcn_s_sleep(2);
                    if (++spins > (1 << 24)) break;   // bounded: bug -> wrong, not hang
                }
                (void)__hip_atomic_load(myflag, __ATOMIC_ACQUIRE,
                                        __HIP_MEMORY_SCOPE_AGENT);
            }
            __syncthreads();   // release whole block; acquire's cache-inv is CU-wide
        }

        const int cur = s & 1;
        const float* h0prev = h0T + (cur ^ 1) * HD * NB;  // h0_{s-1}
        const float* h2prev = h2T + cur * HD * NB;        // h2_{s-2}

        // ---- stage h0,h2 (transposed [b][u']) and x into LDS ----
        {
            const float* s0 = h0prev + (size_t)tid * NB + bg16;
            const float* s2 = h2prev + (size_t)tid * NB + bg16;
            float4 q0 = *(const float4*)(s0 + 0),  q1 = *(const float4*)(s0 + 4);
            float4 q2 = *(const float4*)(s0 + 8),  q3 = *(const float4*)(s0 + 12);
            float4 p0 = *(const float4*)(s2 + 0),  p1 = *(const float4*)(s2 + 4);
            float4 p2 = *(const float4*)(s2 + 8),  p3 = *(const float4*)(s2 + 12);
            h0_lds[ 0][tid]=q0.x; h0_lds[ 1][tid]=q0.y; h0_lds[ 2][tid]=q0.z; h0_lds[ 3][tid]=q0.w;
            h0_lds[ 4][tid]=q1.x; h0_lds[ 5][tid]=q1.y; h0_lds[ 6][tid]=q1.z; h0_lds[ 7][tid]=q1.w;
            h0_lds[ 8][tid]=q2.x; h0_lds[ 9][tid]=q2.y; h0_lds[10][tid]=q2.z; h0_lds[11][tid]=q2.w;
            h0_lds[12][tid]=q3.x; h0_lds[13][tid]=q3.y; h0_lds[14][tid]=q3.z; h0_lds[15][tid]=q3.w;
            h2_lds[ 0][tid]=p0.x; h2_lds[ 1][tid]=p0.y; h2_lds[ 2][tid]=p0.z; h2_lds[ 3][tid]=p0.w;
            h2_lds[ 4][tid]=p1.x; h2_lds[ 5][tid]=p1.y; h2_lds[ 6][tid]=p1.z; h2_lds[ 7][tid]=p1.w;
            h2_lds[ 8][tid]=p2.x; h2_lds[ 9][tid]=p2.y; h2_lds[10][tid]=p2.z; h2_lds[11][tid]=p2.w;
            h2_lds[12][tid]=p3.x; h2_lds[13][tid]=p3.y; h2_lds[14][tid]=p3.z; h2_lds[15][tid]=p3.w;
            if (s < TT)
                *(float4*)&x_lds[xb][xi] = xpf;
        }
        __syncthreads();

        // ================= 4 low-pressure gate passes =================
        // Pass = (layer, gate-pair). Weights streamed per pass (L2-resident;
        // the memory clobber stops LICM from hoisting+spilling them).
        float rA0 = 0.0f, rB0 = 0.0f;   // L0: gates {i,f} and {g,o}
        float rA1 = 0.0f, rB1 = 0.0f;   // L1: gates {i,f} and {g,o}

        if (s < TT) {
            #pragma unroll
            for (int p = 0; p < 2; ++p) {
                asm volatile("" ::: "memory");   // keep weight loads in-loop
                const int g0 = p * 2;
                const size_t ra = (size_t)(g0    ) * HD + us;
                const size_t rbw = (size_t)(g0 + 1) * HD + us;
                const float4 wa0 = *(const float4*)(Whh0 + ra  * HD +       l * 4);
                const float4 wa1 = *(const float4*)(Whh0 + ra  * HD + 256 + l * 4);
                const float4 wb0 = *(const float4*)(Whh0 + rbw * HD +       l * 4);
                const float4 wb1 = *(const float4*)(Whh0 + rbw * HD + 256 + l * 4);
                const float2 xa  = *(const float2*)(Wih0 + ra  * IN + l * 2);
                const float2 xb  = *(const float2*)(Wih0 + rbw * IN + l * 2);
                const float ba = bih0[ra] + bhh0[ra];
                const float bb = bih0[rbw] + bhh0[rbw];
                float A[32];
                #pragma unroll
                for (int j = 0; j < 32; ++j) A[j] = 0.0f;
                #pragma unroll
                for (int b = 0; b < BGB; ++b) {
                    float4 ha = *(const float4*)&h0_lds[b][l * 4];
                    float4 hb = *(const float4*)&h0_lds[b][256 + l * 4];
                    float2 xv = *(const float2*)&x_lds[b][l * 2];
                    A[b]      += dot4(wa0, ha) + dot4(wa1, hb) + xa.x*xv.x + xa.y*xv.y;
                    A[16 + b] += dot4(wb0, ha) + dot4(wb1, hb) + xb.x*xv.x + xb.y*xv.y;
                }
                float r = wave_reduce32(A, l) + (((l >> 4) & 1) ? bb : ba);
                if (p == 0) rA0 = r; else rB0 = r;
            }
        }
        if (s >= 1) {
            #pragma unroll
            for (int p = 0; p < 2; ++p) {
                asm volatile("" ::: "memory");
                const int g0 = p * 2;
                const size_t ra = (size_t)(g0    ) * HD + us;
                const size_t rbw = (size_t)(g0 + 1) * HD + us;
                const float4 ia0 = *(const float4*)(Wih1 + ra  * HD +       l * 4);
                const float4 ia1 = *(const float4*)(Wih1 + ra  * HD + 256 + l * 4);
                const float4 ib0 = *(const float4*)(Wih1 + rbw * HD +       l * 4);
                const float4 ib1 = *(const float4*)(Wih1 + rbw * HD + 256 + l * 4);
                const float4 ja0 = *(const float4*)(Whh1 + ra  * HD +       l * 4);
                const float4 ja1 = *(const float4*)(Whh1 + ra  * HD + 256 + l * 4);
                const float4 jb0 = *(const float4*)(Whh1 + rbw * HD +       l * 4);
                const float4 jb1 = *(const float4*)(Whh1 + rbw * HD + 256 + l * 4);
                const float ba = bih1[ra] + bhh1[ra];
                const float bb = bih1[rbw] + bhh1[rbw];
                float A[32];
                #pragma unroll
                for (int j = 0; j < 32; ++j) A[j] = 0.0f;
                #pragma unroll
                for (int b = 0; b < BGB; ++b) {
                    float4 ha = *(const float4*)&h0_lds[b][l * 4];
                    float4 hb = *(const float4*)&h0_lds[b][256 + l * 4];
                    float4 qa = *(const float4*)&h2_lds[b][l * 4];
                    float4 qb = *(const float4*)&h2_lds[b][256 + l * 4];
                    A[b]      += dot4(ia0, ha) + dot4(ia1, hb) + dot4(ja0, qa) + dot4(ja1, qb);
                    A[16 + b] += dot4(ib0, ha) + dot4(ib1, hb) + dot4(jb0, qa) + dot4(jb1, qb);
                }
                float r = wave_reduce32(A, l) + (((l >> 4) & 1) ? bb : ba);
                if (p == 0) rA1 = r; else rB1 = r;
            }
        }

        // ---- gather gates to lanes 0..15 (shfl by ALL lanes), update state ----
        // pass outputs: rA* -> j=(gate 0/1)*16+b at lane j (dup at j+32);
        //               rB* -> gates 2/3.
        float gi0 = __shfl(rA0, bl,      64);
        float gf0 = __shfl(rA0, bl + 16, 64);
        float gc0 = __shfl(rB0, bl,      64);
        float go0 = __shfl(rB0, bl + 16, 64);
        float gi1 = __shfl(rA1, bl,      64);
        float gf1 = __shfl(rA1, bl + 16, 64);
        float gc1 = __shfl(rB1, bl,      64);
        float go1 = __shfl(rB1, bl + 16, 64);
        if (l < 16) {
            if (s < TT) {
                float cn = sigf(gf0) * c0r + sigf(gi0) * tanhf(gc0);
                c0r = cn;
                h0T[cur * HD * NB + (size_t)u * NB + bg16 + bl] = sigf(go0) * tanhf(cn);
            }
            if (s >= 1) {
                float cn = sigf(gf1) * c2r + sigf(gi1) * tanhf(gc1);
                c2r = cn;
                h2T[(cur ^ 1) * HD * NB + (size_t)u * NB + bg16 + bl] = sigf(go1) * tanhf(cn);
            }
        }

        // ---- arrive ----
        __syncthreads();
        if (tid == 0) {
            __threadfence();
            __hip_atomic_fetch_add(myflag, 1, __ATOMIC_RELEASE,
                                   __HIP_MEMORY_SCOPE_AGENT);
        }
    }

    // ---------------- FC tail: one block per batch group ----------------
    if (rb != 0) return;
    {
        const int target = RBN * (TT + 1);
        if (tid == 0) {
            int spins = 0;
            while (__hip_atomic_load(myflag, __ATOMIC_RELAXED,
                                     __HIP_MEMORY_SCOPE_AGENT) < target) {
                __builtin_amdgcn_s_sleep(2);
                if (++spins > (1 << 24)) break;
            }
            (void)__hip_atomic_load(myflag, __ATOMIC_ACQUIRE,
                                    __HIP_MEMORY_SCOPE_AGENT);
        }
        __syncthreads();

        // h2[TT-1] lives in buffer (TT-1)&1 = 1
        const float* hsrc = h2T + 1 * HD * NB + (size_t)tid * NB + bg16;
        float4 q0 = *(const float4*)(hsrc + 0),  q1 = *(const float4*)(hsrc + 4);
        float4 q2 = *(const float4*)(hsrc + 8),  q3 = *(const float4*)(hsrc + 12);
        h2_lds[ 0][tid]=q0.x; h2_lds[ 1][tid]=q0.y; h2_lds[ 2][tid]=q0.z; h2_lds[ 3][tid]=q0.w;
        h2_lds[ 4][tid]=q1.x; h2_lds[ 5][tid]=q1.y; h2_lds[ 6][tid]=q1.z; h2_lds[ 7][tid]=q1.w;
        h2_lds[ 8][tid]=q2.x; h2_lds[ 9][tid]=q2.y; h2_lds[10][tid]=q2.z; h2_lds[11][tid]=q2.w;
        h2_lds[12][tid]=q3.x; h2_lds[13][tid]=q3.y; h2_lds[14][tid]=q3.z; h2_lds[15][tid]=q3.w;
        __syncthreads();

        const int bb = tid >> 5, oo = tid & 31;
        if (oo < 24) {
            float acc = fcb[oo];
            const float4* hrow = (const float4*)&h2_lds[bb][0];
            const float4* wrow = (const float4*)(fcW + (size_t)oo * HD);
            #pragma unroll 8
            for (int q = 0; q < HD / 4; ++q) acc += dot4(hrow[q], wrow[q]);
            out[(size_t)(bg16 + bb) * 24 + oo] = acc;
        }
    }
}

extern "C" void kernel_launch(void* const* d_in, const int* in_sizes, int n_in,
                              void* d_out, int out_size, void* d_ws, size_t ws_size,
                              hipStream_t stream)
{
    const float* x    = (const float*)d_in[0];
    const float* Wih0 = (const float*)d_in[1];
    const float* Whh0 = (const float*)d_in[2];
    const float* bih0 = (const float*)d_in[3];
    const float* bhh0 = (const float*)d_in[4];
    const float* Wih1 = (const float*)d_in[5];
    const float* Whh1 = (const float*)d_in[6];
    const float* bih1 = (const float*)d_in[7];
    const float* bhh1 = (const float*)d_in[8];
    const float* fcW  = (const float*)d_in[9];
    const float* fcb  = (const float*)d_in[10];

    // zero h ping-pong buffers + flags every call (graph-capture-safe)
    hipMemsetAsync(d_ws, 0, (size_t)(4 * HD * NB) * sizeof(float) + 1024, stream);

    lstm_persist<<<dim3(BGN * RBN), dim3(512), 0, stream>>>(
        x, Wih0, Whh0, bih0, bhh0, Wih1, Whh1, bih1, bhh1, fcW, fcb,
        (float*)d_ws, (float*)d_out);
}

// Round 7
// 11187.437 us; speedup vs baseline: 2.4567x; 2.4567x over previous
//
#include <hip/hip_runtime.h>
#include <math.h>

#define NB 64      // total batch
#define TT 512     // time steps
#define IN 128     // input dim
#define HD 512     // hidden dim
#define BGN 4      // batch groups
#define BGB 16     // batches per group
#define RBN 64     // row-blocks per batch group  (BGN*RBN = 256 blocks)

__device__ __forceinline__ float sigf(float x) { return 1.0f / (1.0f + expf(-x)); }
__device__ __forceinline__ float dot4(float4 a, float4 b) {
    return a.x*b.x + a.y*b.y + a.z*b.z + a.w*b.w;
}

// ---- device-coherent memory ops (bypass L1/L2 -> coherence point) ----
// Used ONLY for the cross-block h ping-pong. Keeps weight/x lines resident in
// L2 across all 512 steps because no acquire-invalidate is ever issued.
__device__ __forceinline__ void load_coh16(const float* p,
                                           float4& a, float4& b,
                                           float4& c, float4& d) {
    asm volatile(
        "global_load_dwordx4 %0, %4, off sc0 sc1\n\t"
        "global_load_dwordx4 %1, %4, off offset:16 sc0 sc1\n\t"
        "global_load_dwordx4 %2, %4, off offset:32 sc0 sc1\n\t"
        "global_load_dwordx4 %3, %4, off offset:48 sc0 sc1"
        : "=&v"(a), "=&v"(b), "=&v"(c), "=&v"(d)
        : "v"(p)
        : "memory");
}
__device__ __forceinline__ void wait_vm0() {
    asm volatile("s_waitcnt vmcnt(0)" ::: "memory");
}
__device__ __forceinline__ void store_coh(float* p, float v) {
    asm volatile("global_store_dword %0, %1, off sc0 sc1"
                 :: "v"(p), "v"(v) : "memory");
}

// 6-step butterfly over 64 lanes: on entry lane l holds partials A[j] (j=0..63,
// its k-slice's contribution to output j). On exit returns full sum for j = l.
__device__ __forceinline__ float wave_reduce64(float* A, int l) {
    #pragma unroll
    for (int s = 0; s < 6; ++s) {
        const int m = 1 << s;
        const bool bit = (l >> s) & 1;
        const int cnt = 64 >> (s + 1);
        #pragma unroll
        for (int i = 0; i < cnt; ++i) {
            float send = bit ? A[2*i]     : A[2*i + 1];
            float keep = bit ? A[2*i + 1] : A[2*i];
            float recv = __shfl_xor(send, m, 64);
            A[i] = keep + recv;
        }
    }
    return A[0];
}

// ws layout (floats): h0T[2][HD][NB] | h2T[2][HD][NB] | flags (ints, 64B-strided)
// Pipeline step s: L0 computes h0_s from h0_{s-1}; L1 computes h2_{s-1} from
// h0_{s-1} and h2_{s-2}.  cur=s&1: read h0T[cur^1], h2T[cur]; write h0T[cur],
// h2T[cur^1]  (identical to the verified Round-0/2/3/4 convention).
__global__ __launch_bounds__(512, 2) void lstm_persist(
    const float* __restrict__ x,
    const float* __restrict__ Wih0, const float* __restrict__ Whh0,
    const float* __restrict__ bih0, const float* __restrict__ bhh0,
    const float* __restrict__ Wih1, const float* __restrict__ Whh1,
    const float* __restrict__ bih1, const float* __restrict__ bhh1,
    const float* __restrict__ fcW, const float* __restrict__ fcb,
    float* __restrict__ ws, float* __restrict__ out)
{
    __shared__ float x_lds[BGB][IN];    // 8 KB
    __shared__ float h0_lds[BGB][HD];   // 32 KB   [b][u'] transposed
    __shared__ float h2_lds[BGB][HD];   // 32 KB

    const int tid = threadIdx.x;
    const int l   = tid & 63;          // lane
    const int w   = tid >> 6;          // wave 0..7
    const int bg  = blockIdx.x & 3;    // batch group
    const int rb  = blockIdx.x >> 2;   // row-block 0..63
    const int u   = rb * 8 + w;        // unit owned by this wave (both layers)
    const int bg16 = bg * BGB;
    const int bl  = l & 15;            // state-batch lane

    float* h0T = ws;                       // [2][HD][NB]
    float* h2T = ws + 2 * HD * NB;         // [2][HD][NB]
    int*  flags = (int*)(ws + 4 * HD * NB);

    // ---------------- prologue: weight/bias pointers (loads stream per step,
    // L2-resident — they stay hot because nothing invalidates L2 anymore) ----
    const float b0i = bih0[0*HD+u] + bhh0[0*HD+u];
    const float b0f = bih0[1*HD+u] + bhh0[1*HD+u];
    const float b0c = bih0[2*HD+u] + bhh0[2*HD+u];
    const float b0o = bih0[3*HD+u] + bhh0[3*HD+u];
    const float b1i = bih1[0*HD+u] + bhh1[0*HD+u];
    const float b1f = bih1[1*HD+u] + bhh1[1*HD+u];
    const float b1c = bih1[2*HD+u] + bhh1[2*HD+u];
    const float b1o = bih1[3*HD+u] + bhh1[3*HD+u];
    const float bias0 = (l & 32) ? ((l & 16) ? b0o : b0c) : ((l & 16) ? b0f : b0i);
    const float bias1 = (l & 32) ? ((l & 16) ? b1o : b1c) : ((l & 16) ? b1f : b1i);

    float c0r = 0.0f, c2r = 0.0f;      // cell state, valid on lanes 0..15

    int* myflag = flags + bg * 16;     // 64B-strided

    for (int s = 0; s <= TT; ++s) {
        // ---- T14: issue x load for step s before the barrier (x is input) ----
        float4 xpf;
        const int xb = tid >> 5, xi = (tid & 31) * 4;
        if (s < TT)
            xpf = *(const float4*)(x + ((size_t)(bg16 + xb) * TT + s) * IN + xi);

        // ---- batch-group barrier: single poller per block, NO invalidate ----
        const int target = RBN * s;
        if (s > 0) {
            if (tid == 0) {
                int spins = 0;
                while (__hip_atomic_load(myflag, __ATOMIC_RELAXED,
                                         __HIP_MEMORY_SCOPE_AGENT) < target) {
                    __builtin_amdgcn_s_sleep(2);
                    if (++spins > (1 << 24)) break;   // bounded: bug -> wrong, not hang
                }
            }
            __syncthreads();   // release whole block; h reads below are coherent
        }

        const int cur = s & 1;
        const float* h0prev = h0T + (cur ^ 1) * HD * NB;  // h0_{s-1}
        const float* h2prev = h2T + cur * HD * NB;        // h2_{s-2}

        // ---- stage h0,h2 (coherent reads; transposed [b][u']) + x into LDS ----
        {
            const float* s0 = h0prev + (size_t)tid * NB + bg16;
            const float* s2 = h2prev + (size_t)tid * NB + bg16;
            float4 q0, q1, q2, q3, p0, p1, p2, p3;
            load_coh16(s0, q0, q1, q2, q3);
            load_coh16(s2, p0, p1, p2, p3);
            wait_vm0();
            h0_lds[ 0][tid]=q0.x; h0_lds[ 1][tid]=q0.y; h0_lds[ 2][tid]=q0.z; h0_lds[ 3][tid]=q0.w;
            h0_lds[ 4][tid]=q1.x; h0_lds[ 5][tid]=q1.y; h0_lds[ 6][tid]=q1.z; h0_lds[ 7][tid]=q1.w;
            h0_lds[ 8][tid]=q2.x; h0_lds[ 9][tid]=q2.y; h0_lds[10][tid]=q2.z; h0_lds[11][tid]=q2.w;
            h0_lds[12][tid]=q3.x; h0_lds[13][tid]=q3.y; h0_lds[14][tid]=q3.z; h0_lds[15][tid]=q3.w;
            h2_lds[ 0][tid]=p0.x; h2_lds[ 1][tid]=p0.y; h2_lds[ 2][tid]=p0.z; h2_lds[ 3][tid]=p0.w;
            h2_lds[ 4][tid]=p1.x; h2_lds[ 5][tid]=p1.y; h2_lds[ 6][tid]=p1.z; h2_lds[ 7][tid]=p1.w;
            h2_lds[ 8][tid]=p2.x; h2_lds[ 9][tid]=p2.y; h2_lds[10][tid]=p2.z; h2_lds[11][tid]=p2.w;
            h2_lds[12][tid]=p3.x; h2_lds[13][tid]=p3.y; h2_lds[14][tid]=p3.z; h2_lds[15][tid]=p3.w;
            if (s < TT)
                *(float4*)&x_lds[xb][xi] = xpf;
        }
        __syncthreads();

        float r0 = 0.0f, r1 = 0.0f;

        // ---- layer0: gates for (unit u, all 16 batches) ----
        if (s < TT) {
            float A[64];
            #pragma unroll
            for (int j = 0; j < 64; ++j) A[j] = 0.0f;
            #pragma unroll
            for (int b = 0; b < BGB; ++b) {
                float4 ha = *(const float4*)&h0_lds[b][l * 4];
                float4 hb = *(const float4*)&h0_lds[b][256 + l * 4];
                float2 xv = *(const float2*)&x_lds[b][l * 2];
                #pragma unroll
                for (int g = 0; g < 4; ++g) {
                    const size_t r = (size_t)g * HD + u;
                    float4 wa = *(const float4*)(Whh0 + r * HD +       l * 4);
                    float4 wb = *(const float4*)(Whh0 + r * HD + 256 + l * 4);
                    float2 wx = *(const float2*)(Wih0 + r * IN + l * 2);
                    A[g * 16 + b] += dot4(wa, ha) + dot4(wb, hb)
                                   + wx.x * xv.x + wx.y * xv.y;
                }
            }
            r0 = wave_reduce64(A, l) + bias0;
        }
        // ---- layer1: gates for (unit u, all 16 batches) ----
        if (s >= 1) {
            float A[64];
            #pragma unroll
            for (int j = 0; j < 64; ++j) A[j] = 0.0f;
            #pragma unroll
            for (int b = 0; b < BGB; ++b) {
                float4 ha = *(const float4*)&h0_lds[b][l * 4];
                float4 hb = *(const float4*)&h0_lds[b][256 + l * 4];
                float4 qa = *(const float4*)&h2_lds[b][l * 4];
                float4 qb = *(const float4*)&h2_lds[b][256 + l * 4];
                #pragma unroll
                for (int g = 0; g < 4; ++g) {
                    const size_t r = (size_t)g * HD + u;
                    float4 wi0 = *(const float4*)(Wih1 + r * HD +       l * 4);
                    float4 wi1 = *(const float4*)(Wih1 + r * HD + 256 + l * 4);
                    float4 wh0 = *(const float4*)(Whh1 + r * HD +       l * 4);
                    float4 wh1 = *(const float4*)(Whh1 + r * HD + 256 + l * 4);
                    A[g * 16 + b] += dot4(wi0, ha) + dot4(wi1, hb)
                                   + dot4(wh0, qa) + dot4(wh1, qb);
                }
            }
            r1 = wave_reduce64(A, l) + bias1;
        }

        // ---- gather gates to lanes 0..15 (shfl by ALL lanes), update state ----
        float gi0 = __shfl(r0, bl,      64);
        float gf0 = __shfl(r0, bl + 16, 64);
        float gc0 = __shfl(r0, bl + 32, 64);
        float go0 = __shfl(r0, bl + 48, 64);
        float gi1 = __shfl(r1, bl,      64);
        float gf1 = __shfl(r1, bl + 16, 64);
        float gc1 = __shfl(r1, bl + 32, 64);
        float go1 = __shfl(r1, bl + 48, 64);
        if (l < 16) {
            if (s < TT) {
                float cn = sigf(gf0) * c0r + sigf(gi0) * tanhf(gc0);
                c0r = cn;
                store_coh(h0T + cur * HD * NB + (size_t)u * NB + bg16 + bl,
                          sigf(go0) * tanhf(cn));
            }
            if (s >= 1) {
                float cn = sigf(gf1) * c2r + sigf(gi1) * tanhf(gc1);
                c2r = cn;
                store_coh(h2T + (cur ^ 1) * HD * NB + (size_t)u * NB + bg16 + bl,
                          sigf(go1) * tanhf(cn));   // h2_{s-1}
            }
        }

        // ---- arrive: syncthreads drains each wave's stores (vmcnt) first ----
        __syncthreads();
        if (tid == 0) {
            __hip_atomic_fetch_add(myflag, 1, __ATOMIC_RELEASE,
                                   __HIP_MEMORY_SCOPE_AGENT);
        }
    }

    // ---------------- FC tail: one block per batch group ----------------
    if (rb != 0) return;
    {
        const int target = RBN * (TT + 1);
        if (tid == 0) {
            int spins = 0;
            while (__hip_atomic_load(myflag, __ATOMIC_RELAXED,
                                     __HIP_MEMORY_SCOPE_AGENT) < target) {
                __builtin_amdgcn_s_sleep(2);
                if (++spins > (1 << 24)) break;
            }
        }
        __syncthreads();

        // h2[TT-1] lives in buffer (TT-1)&1 = 1  (coherent reads)
        const float* hsrc = h2T + 1 * HD * NB + (size_t)tid * NB + bg16;
        float4 q0, q1, q2, q3;
        load_coh16(hsrc, q0, q1, q2, q3);
        wait_vm0();
        h2_lds[ 0][tid]=q0.x; h2_lds[ 1][tid]=q0.y; h2_lds[ 2][tid]=q0.z; h2_lds[ 3][tid]=q0.w;
        h2_lds[ 4][tid]=q1.x; h2_lds[ 5][tid]=q1.y; h2_lds[ 6][tid]=q1.z; h2_lds[ 7][tid]=q1.w;
        h2_lds[ 8][tid]=q2.x; h2_lds[ 9][tid]=q2.y; h2_lds[10][tid]=q2.z; h2_lds[11][tid]=q2.w;
        h2_lds[12][tid]=q3.x; h2_lds[13][tid]=q3.y; h2_lds[14][tid]=q3.z; h2_lds[15][tid]=q3.w;
        __syncthreads();

        const int bb = tid >> 5, oo = tid & 31;
        if (oo < 24) {
            float acc = fcb[oo];
            const float4* hrow = (const float4*)&h2_lds[bb][0];
            const float4* wrow = (const float4*)(fcW + (size_t)oo * HD);
            #pragma unroll 8
            for (int q = 0; q < HD / 4; ++q) acc += dot4(hrow[q], wrow[q]);
            out[(size_t)(bg16 + bb) * 24 + oo] = acc;
        }
    }
}

extern "C" void kernel_launch(void* const* d_in, const int* in_sizes, int n_in,
                              void* d_out, int out_size, void* d_ws, size_t ws_size,
                              hipStream_t stream)
{
    const float* x    = (const float*)d_in[0];
    const float* Wih0 = (const float*)d_in[1];
    const float* Whh0 = (const float*)d_in[2];
    const float* bih0 = (const float*)d_in[3];
    const float* bhh0 = (const float*)d_in[4];
    const float* Wih1 = (const float*)d_in[5];
    const float* Whh1 = (const float*)d_in[6];
    const float* bih1 = (const float*)d_in[7];
    const float* bhh1 = (const float*)d_in[8];
    const float* fcW  = (const float*)d_in[9];
    const float* fcb  = (const float*)d_in[10];

    // zero h ping-pong buffers + flags every call (graph-capture-safe)
    hipMemsetAsync(d_ws, 0, (size_t)(4 * HD * NB) * sizeof(float) + 1024, stream);

    lstm_persist<<<dim3(BGN * RBN), dim3(512), 0, stream>>>(
        x, Wih0, Whh0, bih0, bhh0, Wih1, Whh1, bih1, bhh1, fcW, fcb,
        (float*)d_ws, (float*)d_out);
}

// Round 8
// 9726.057 us; speedup vs baseline: 2.8258x; 1.1503x over previous
//
#include <hip/hip_runtime.h>
#include <math.h>

#define NB 64      // total batch
#define TT 512     // time steps
#define IN 128     // input dim
#define HD 512     // hidden dim
#define BGN 4      // batch groups
#define BGB 16     // batches per group
#define RBN 64     // row-blocks per batch group  (BGN*RBN = 256 blocks)

__device__ __forceinline__ float sigf(float x) { return 1.0f / (1.0f + expf(-x)); }
__device__ __forceinline__ float dot4(float4 a, float4 b) {
    return a.x*b.x + a.y*b.y + a.z*b.z + a.w*b.w;
}

// ---- device-coherent memory ops (bypass L1/L2 -> coherence point) ----
// Used ONLY for the cross-block h ping-pong. Keeps weight/x lines resident in
// L2 across all 512 steps because no acquire-invalidate is ever issued.
__device__ __forceinline__ void load_coh16(const float* p,
                                           float4& a, float4& b,
                                           float4& c, float4& d) {
    asm volatile(
        "global_load_dwordx4 %0, %4, off sc0 sc1\n\t"
        "global_load_dwordx4 %1, %4, off offset:16 sc0 sc1\n\t"
        "global_load_dwordx4 %2, %4, off offset:32 sc0 sc1\n\t"
        "global_load_dwordx4 %3, %4, off offset:48 sc0 sc1"
        : "=&v"(a), "=&v"(b), "=&v"(c), "=&v"(d)
        : "v"(p)
        : "memory");
}
__device__ __forceinline__ void wait_vm0() {
    asm volatile("s_waitcnt vmcnt(0)" ::: "memory");
}
__device__ __forceinline__ void store_coh(float* p, float v) {
    asm volatile("global_store_dword %0, %1, off sc0 sc1"
                 :: "v"(p), "v"(v) : "memory");
}

// 6-step butterfly over 64 lanes: on entry lane l holds partials A[j] (j=0..63,
// its k-slice's contribution to output j). On exit returns full sum for j = l.
__device__ __forceinline__ float wave_reduce64(float* A, int l) {
    #pragma unroll
    for (int s = 0; s < 6; ++s) {
        const int m = 1 << s;
        const bool bit = (l >> s) & 1;
        const int cnt = 64 >> (s + 1);
        #pragma unroll
        for (int i = 0; i < cnt; ++i) {
            float send = bit ? A[2*i]     : A[2*i + 1];
            float keep = bit ? A[2*i + 1] : A[2*i];
            float recv = __shfl_xor(send, m, 64);
            A[i] = keep + recv;
        }
    }
    return A[0];
}

// ws layout (floats): h0T[2][HD][NB] | h2T[2][HD][NB] | flags (ints, 64B-strided)
// Pipeline step s: L0 computes h0_s from h0_{s-1}; L1 computes h2_{s-1} from
// h0_{s-1} and h2_{s-2}.  cur=s&1: read h0T[cur^1], h2T[cur]; write h0T[cur],
// h2T[cur^1]  (identical to the verified Round-0/2/3/4/6 convention).
__global__ __launch_bounds__(512, 2) void lstm_persist(
    const float* __restrict__ x,
    const float* __restrict__ Wih0, const float* __restrict__ Whh0,
    const float* __restrict__ bih0, const float* __restrict__ bhh0,
    const float* __restrict__ Wih1, const float* __restrict__ Whh1,
    const float* __restrict__ bih1, const float* __restrict__ bhh1,
    const float* __restrict__ fcW, const float* __restrict__ fcb,
    float* __restrict__ ws, float* __restrict__ out)
{
    __shared__ float x_lds[BGB][IN];    // 8 KB
    __shared__ float h0_lds[BGB][HD];   // 32 KB   [b][u'] transposed
    __shared__ float h2_lds[BGB][HD];   // 32 KB

    const int tid = threadIdx.x;
    const int l   = tid & 63;          // lane
    const int w   = tid >> 6;          // wave 0..7

    // ---- XCD-aware placement (T1): blocks round-robin across 8 XCDs, so put
    // 8 row-blocks x 4 batch-groups on each XCD. Per-XCD weight footprint:
    // 64 units x 26.6 KB = 1.7 MB < 4 MiB L2 (old mapping: 6.8 MB -> thrash).
    // Bijective (rb,bg) <-> blockIdx, so correctness is placement-independent.
    const int xcd  = blockIdx.x & 7;
    const int slot = blockIdx.x >> 3;     // 0..31 within XCD
    const int rb   = xcd * 8 + (slot >> 2);  // row-block 0..63
    const int bg   = slot & 3;               // batch group

    const int u   = rb * 8 + w;        // unit owned by this wave (both layers)
    const int bg16 = bg * BGB;
    const int bl  = l & 15;            // state-batch lane

    float* h0T = ws;                       // [2][HD][NB]
    float* h2T = ws + 2 * HD * NB;         // [2][HD][NB]
    int*  flags = (int*)(ws + 4 * HD * NB);

    // ---------------- prologue: bias setup (weights stream per step from the
    // now-resident L2; nothing invalidates them) ----
    const float b0i = bih0[0*HD+u] + bhh0[0*HD+u];
    const float b0f = bih0[1*HD+u] + bhh0[1*HD+u];
    const float b0c = bih0[2*HD+u] + bhh0[2*HD+u];
    const float b0o = bih0[3*HD+u] + bhh0[3*HD+u];
    const float b1i = bih1[0*HD+u] + bhh1[0*HD+u];
    const float b1f = bih1[1*HD+u] + bhh1[1*HD+u];
    const float b1c = bih1[2*HD+u] + bhh1[2*HD+u];
    const float b1o = bih1[3*HD+u] + bhh1[3*HD+u];
    const float bias0 = (l & 32) ? ((l & 16) ? b0o : b0c) : ((l & 16) ? b0f : b0i);
    const float bias1 = (l & 32) ? ((l & 16) ? b1o : b1c) : ((l & 16) ? b1f : b1i);

    float c0r = 0.0f, c2r = 0.0f;      // cell state, valid on lanes 0..15

    int* myflag = flags + bg * 16;     // 64B-strided

    for (int s = 0; s <= TT; ++s) {
        // ---- T14: issue x load for step s before the barrier (x is input) ----
        float4 xpf;
        const int xb = tid >> 5, xi = (tid & 31) * 4;
        if (s < TT)
            xpf = *(const float4*)(x + ((size_t)(bg16 + xb) * TT + s) * IN + xi);

        // ---- batch-group barrier: single poller per block, NO invalidate ----
        const int target = RBN * s;
        if (s > 0) {
            if (tid == 0) {
                int spins = 0;
                while (__hip_atomic_load(myflag, __ATOMIC_RELAXED,
                                         __HIP_MEMORY_SCOPE_AGENT) < target) {
                    __builtin_amdgcn_s_sleep(2);
                    if (++spins > (1 << 24)) break;   // bounded: bug -> wrong, not hang
                }
            }
            __syncthreads();   // release whole block; h reads below are coherent
        }

        const int cur = s & 1;
        const float* h0prev = h0T + (cur ^ 1) * HD * NB;  // h0_{s-1}
        const float* h2prev = h2T + cur * HD * NB;        // h2_{s-2}

        // ---- stage h0,h2 (coherent reads; transposed [b][u']) + x into LDS ----
        {
            const float* s0 = h0prev + (size_t)tid * NB + bg16;
            const float* s2 = h2prev + (size_t)tid * NB + bg16;
            float4 q0, q1, q2, q3, p0, p1, p2, p3;
            load_coh16(s0, q0, q1, q2, q3);
            load_coh16(s2, p0, p1, p2, p3);
            wait_vm0();
            h0_lds[ 0][tid]=q0.x; h0_lds[ 1][tid]=q0.y; h0_lds[ 2][tid]=q0.z; h0_lds[ 3][tid]=q0.w;
            h0_lds[ 4][tid]=q1.x; h0_lds[ 5][tid]=q1.y; h0_lds[ 6][tid]=q1.z; h0_lds[ 7][tid]=q1.w;
            h0_lds[ 8][tid]=q2.x; h0_lds[ 9][tid]=q2.y; h0_lds[10][tid]=q2.z; h0_lds[11][tid]=q2.w;
            h0_lds[12][tid]=q3.x; h0_lds[13][tid]=q3.y; h0_lds[14][tid]=q3.z; h0_lds[15][tid]=q3.w;
            h2_lds[ 0][tid]=p0.x; h2_lds[ 1][tid]=p0.y; h2_lds[ 2][tid]=p0.z; h2_lds[ 3][tid]=p0.w;
            h2_lds[ 4][tid]=p1.x; h2_lds[ 5][tid]=p1.y; h2_lds[ 6][tid]=p1.z; h2_lds[ 7][tid]=p1.w;
            h2_lds[ 8][tid]=p2.x; h2_lds[ 9][tid]=p2.y; h2_lds[10][tid]=p2.z; h2_lds[11][tid]=p2.w;
            h2_lds[12][tid]=p3.x; h2_lds[13][tid]=p3.y; h2_lds[14][tid]=p3.z; h2_lds[15][tid]=p3.w;
            if (s < TT)
                *(float4*)&x_lds[xb][xi] = xpf;
        }
        __syncthreads();

        float r0 = 0.0f, r1 = 0.0f;

        // ---- layer0: gates for (unit u, all 16 batches) ----
        if (s < TT) {
            float A[64];
            #pragma unroll
            for (int j = 0; j < 64; ++j) A[j] = 0.0f;
            #pragma unroll
            for (int b = 0; b < BGB; ++b) {
                float4 ha = *(const float4*)&h0_lds[b][l * 4];
                float4 hb = *(const float4*)&h0_lds[b][256 + l * 4];
                float2 xv = *(const float2*)&x_lds[b][l * 2];
                #pragma unroll
                for (int g = 0; g < 4; ++g) {
                    const size_t r = (size_t)g * HD + u;
                    float4 wa = *(const float4*)(Whh0 + r * HD +       l * 4);
                    float4 wb = *(const float4*)(Whh0 + r * HD + 256 + l * 4);
                    float2 wx = *(const float2*)(Wih0 + r * IN + l * 2);
                    A[g * 16 + b] += dot4(wa, ha) + dot4(wb, hb)
                                   + wx.x * xv.x + wx.y * xv.y;
                }
            }
            r0 = wave_reduce64(A, l) + bias0;
        }
        // ---- layer1: gates for (unit u, all 16 batches) ----
        if (s >= 1) {
            float A[64];
            #pragma unroll
            for (int j = 0; j < 64; ++j) A[j] = 0.0f;
            #pragma unroll
            for (int b = 0; b < BGB; ++b) {
                float4 ha = *(const float4*)&h0_lds[b][l * 4];
                float4 hb = *(const float4*)&h0_lds[b][256 + l * 4];
                float4 qa = *(const float4*)&h2_lds[b][l * 4];
                float4 qb = *(const float4*)&h2_lds[b][256 + l * 4];
                #pragma unroll
                for (int g = 0; g < 4; ++g) {
                    const size_t r = (size_t)g * HD + u;
                    float4 wi0 = *(const float4*)(Wih1 + r * HD +       l * 4);
                    float4 wi1 = *(const float4*)(Wih1 + r * HD + 256 + l * 4);
                    float4 wh0 = *(const float4*)(Whh1 + r * HD +       l * 4);
                    float4 wh1 = *(const float4*)(Whh1 + r * HD + 256 + l * 4);
                    A[g * 16 + b] += dot4(wi0, ha) + dot4(wi1, hb)
                                   + dot4(wh0, qa) + dot4(wh1, qb);
                }
            }
            r1 = wave_reduce64(A, l) + bias1;
        }

        // ---- gather gates to lanes 0..15 (shfl by ALL lanes), update state ----
        float gi0 = __shfl(r0, bl,      64);
        float gf0 = __shfl(r0, bl + 16, 64);
        float gc0 = __shfl(r0, bl + 32, 64);
        float go0 = __shfl(r0, bl + 48, 64);
        float gi1 = __shfl(r1, bl,      64);
        float gf1 = __shfl(r1, bl + 16, 64);
        float gc1 = __shfl(r1, bl + 32, 64);
        float go1 = __shfl(r1, bl + 48, 64);
        if (l < 16) {
            if (s < TT) {
                float cn = sigf(gf0) * c0r + sigf(gi0) * tanhf(gc0);
                c0r = cn;
                store_coh(h0T + cur * HD * NB + (size_t)u * NB + bg16 + bl,
                          sigf(go0) * tanhf(cn));
            }
            if (s >= 1) {
                float cn = sigf(gf1) * c2r + sigf(gi1) * tanhf(gc1);
                c2r = cn;
                store_coh(h2T + (cur ^ 1) * HD * NB + (size_t)u * NB + bg16 + bl,
                          sigf(go1) * tanhf(cn));   // h2_{s-1}
            }
        }

        // ---- arrive: syncthreads drains each wave's stores (vmcnt) first ----
        __syncthreads();
        if (tid == 0) {
            __hip_atomic_fetch_add(myflag, 1, __ATOMIC_RELEASE,
                                   __HIP_MEMORY_SCOPE_AGENT);
        }
    }

    // ---------------- FC tail: one block per batch group ----------------
    if (rb != 0) return;
    {
        const int target = RBN * (TT + 1);
        if (tid == 0) {
            int spins = 0;
            while (__hip_atomic_load(myflag, __ATOMIC_RELAXED,
                                     __HIP_MEMORY_SCOPE_AGENT) < target) {
                __builtin_amdgcn_s_sleep(2);
                if (++spins > (1 << 24)) break;
            }
        }
        __syncthreads();

        // h2[TT-1] lives in buffer (TT-1)&1 = 1  (coherent reads)
        const float* hsrc = h2T + 1 * HD * NB + (size_t)tid * NB + bg16;
        float4 q0, q1, q2, q3;
        load_coh16(hsrc, q0, q1, q2, q3);
        wait_vm0();
        h2_lds[ 0][tid]=q0.x; h2_lds[ 1][tid]=q0.y; h2_lds[ 2][tid]=q0.z; h2_lds[ 3][tid]=q0.w;
        h2_lds[ 4][tid]=q1.x; h2_lds[ 5][tid]=q1.y; h2_lds[ 6][tid]=q1.z; h2_lds[ 7][tid]=q1.w;
        h2_lds[ 8][tid]=q2.x; h2_lds[ 9][tid]=q2.y; h2_lds[10][tid]=q2.z; h2_lds[11][tid]=q2.w;
        h2_lds[12][tid]=q3.x; h2_lds[13][tid]=q3.y; h2_lds[14][tid]=q3.z; h2_lds[15][tid]=q3.w;
        __syncthreads();

        const int bb = tid >> 5, oo = tid & 31;
        if (oo < 24) {
            float acc = fcb[oo];
            const float4* hrow = (const float4*)&h2_lds[bb][0];
            const float4* wrow = (const float4*)(fcW + (size_t)oo * HD);
            #pragma unroll 8
            for (int q = 0; q < HD / 4; ++q) acc += dot4(hrow[q], wrow[q]);
            out[(size_t)(bg16 + bb) * 24 + oo] = acc;
        }
    }
}

extern "C" void kernel_launch(void* const* d_in, const int* in_sizes, int n_in,
                              void* d_out, int out_size, void* d_ws, size_t ws_size,
                              hipStream_t stream)
{
    const float* x    = (const float*)d_in[0];
    const float* Wih0 = (const float*)d_in[1];
    const float* Whh0 = (const float*)d_in[2];
    const float* bih0 = (const float*)d_in[3];
    const float* bhh0 = (const float*)d_in[4];
    const float* Wih1 = (const float*)d_in[5];
    const float* Whh1 = (const float*)d_in[6];
    const float* bih1 = (const float*)d_in[7];
    const float* bhh1 = (const float*)d_in[8];
    const float* fcW  = (const float*)d_in[9];
    const float* fcb  = (const float*)d_in[10];

    // zero h ping-pong buffers + flags every call (graph-capture-safe)
    hipMemsetAsync(d_ws, 0, (size_t)(4 * HD * NB) * sizeof(float) + 1024, stream);

    lstm_persist<<<dim3(BGN * RBN), dim3(512), 0, stream>>>(
        x, Wih0, Whh0, bih0, bhh0, Wih1, Whh1, bih1, bhh1, fcW, fcb,
        (float*)d_ws, (float*)d_out);
}